// Round 6
// baseline (267.605 us; speedup 1.0000x reference)
//
#include <hip/hip_runtime.h>

typedef unsigned short u16;
typedef unsigned int u32;
typedef __attribute__((ext_vector_type(4))) float floatx4;
typedef __attribute__((ext_vector_type(16))) float floatx16;
typedef __attribute__((ext_vector_type(8))) __bf16 bf16x8;
typedef __attribute__((ext_vector_type(2))) unsigned int u32x2;
typedef __attribute__((ext_vector_type(4))) unsigned int u32x4;

#define MFMA_BF16(a, b, c) __builtin_amdgcn_mfma_f32_16x16x32_bf16((a), (b), (c), 0, 0, 0)
#define MFMA32(a, b, c) __builtin_amdgcn_mfma_f32_32x32x16_bf16((a), (b), (c), 0, 0, 0)

typedef const __attribute__((address_space(1))) void* gas_ptr;
typedef __attribute__((address_space(3))) void* las_ptr;

__device__ __forceinline__ void gll16(const void* g, void* l) {
  __builtin_amdgcn_global_load_lds((gas_ptr)g, (las_ptr)l, 16, 0, 0);
}

__device__ __forceinline__ u16 f2bf(float x) {
  u32 u = __builtin_bit_cast(u32, x);
  u = (u + 0x7fffu + ((u >> 16) & 1u)) >> 16;
  return (u16)u;
}

__device__ __forceinline__ u32 cvtpk(float lo, float hi) {
  u32 r;
  asm("v_cvt_pk_bf16_f32 %0, %1, %2" : "=v"(r) : "v"(lo), "v"(hi));
  return r;
}

// ---------------------------------------------------------------------------
// Kernel 1: down/up vectors from palette.
// ---------------------------------------------------------------------------
__global__ void prep_downup(const float* __restrict__ pal,
                            const float* __restrict__ qd, const float* __restrict__ qu,
                            const float* __restrict__ kd, const float* __restrict__ ku,
                            const float* __restrict__ vd, const float* __restrict__ vu,
                            const float* __restrict__ od, const float* __restrict__ ou,
                            float* __restrict__ down_f, float* __restrict__ up_f) {
  int tid = blockIdx.x * blockDim.x + threadIdx.x;
  int w = tid / 10240;
  int rem = tid - w * 10240;
  const float* dsrc = (w == 0) ? qd : (w == 1) ? kd : (w == 2) ? vd : od;
  const float* usrc = (w == 0) ? qu : (w == 1) ? ku : (w == 2) ? vu : ou;
  bool isdown = rem < 5120;
  int row = isdown ? rem : rem - 5120;
  const float* src = (isdown ? dsrc : usrc) + row * 15;
  float s = 0.f;
#pragma unroll
  for (int p = 0; p < 15; ++p) s += pal[p] * src[p];
  if (isdown) down_f[w * 5120 + row] = s;
  else        up_f[w * 5120 + row] = s;
}

// ---------------------------------------------------------------------------
// Kernel 2 (fused): blocks [0,25600): W_eff build; blocks [25600,30720):
// cvt_x (x fp32 -> bf16).  Independent work, one launch saved.
// ---------------------------------------------------------------------------
__global__ void build_weff_cvtx(const float* __restrict__ Wq, const float* __restrict__ Wk,
                                const float* __restrict__ Wv, const float* __restrict__ Wo,
                                const float* __restrict__ down_f, const float* __restrict__ up_f,
                                u16* __restrict__ weff_qkv, u16* __restrict__ weff_o,
                                const float4* __restrict__ x, ushort4* __restrict__ xb) {
  if (blockIdx.x >= 25600) {
    int i = (blockIdx.x - 25600) * blockDim.x + threadIdx.x;  // 1310720
    float4 v = x[i];
    ushort4 o;
    o.x = f2bf(v.x); o.y = f2bf(v.y); o.z = f2bf(v.z); o.w = f2bf(v.w);
    xb[i] = o;
    return;
  }
  int tid = blockIdx.x * blockDim.x + threadIdx.x;  // 4 * 1638400
  int w = tid / 1638400;
  int rem = tid - w * 1638400;
  int n = rem / 1280;
  int k = rem - n * 1280;
  const float* W = (w == 0) ? Wq : (w == 1) ? Wk : (w == 2) ? Wv : Wo;
  const float* up = up_f + w * 5120 + n * 4;
  const float* dn = down_f + w * 5120 + k;
  float v = W[rem] + up[0] * dn[0] + up[1] * dn[1280] + up[2] * dn[2560] + up[3] * dn[3840];
  u16 hv = f2bf(v);
  if (w < 3) weff_qkv[w * 1638400 + rem] = hv;
  else       weff_o[rem] = hv;
}

// ---------------------------------------------------------------------------
// QKV GEMM (R3-proven 128x128 structure) + fused V transpose.
// C[M,N] = A[M,K] @ B[N,K]^T.  128x128 tile, BK=64, rotate-by-row k-chunk
// staging swizzle (conflict-free fragment reads).  Epilogue: q/k blocks
// (bn<2560) write natural coalesced bf16; V blocks (bn>=2560, 128-aligned)
// scatter C into a 128x136-stride LDS tile (overlaid on lA/lB; 34.8 KB)
// then store vtb[(b*1280+n)*2048+s] coalesced 16B/lane -- replaces the
// standalone vtrans kernel.
// ---------------------------------------------------------------------------
__global__ __launch_bounds__(256) void gemm128_qkv(const u16* __restrict__ A, const u16* __restrict__ Bm,
                                                   u16* __restrict__ qb, u16* __restrict__ kb,
                                                   u16* __restrict__ vtb, int K) {
  __shared__ __align__(16) u16 smem[128 * 136];  // loop: lA=smem[0:8192], lB=smem[8192:16384]
  u16* lA = smem;
  u16* lB = smem + 8192;
  const int t = threadIdx.x;
  const int lane = t & 63;
  const int l15 = lane & 15, quad = lane >> 4;
  const int wid = t >> 6;
  const int wm = (wid >> 1) * 64;
  const int wn = (wid & 1) * 64;
  const int bm = blockIdx.x * 128;
  const int bn = blockIdx.y * 128;
  floatx4 acc[4][4] = {};

  // Staging slot -> global offset (slot c: row=c>>3, pos=c&7, chunk=(pos+row)&7).
  int soff[4];
#pragma unroll
  for (int i = 0; i < 4; ++i) {
    int c = t + i * 256;
    int row = c >> 3, pos = c & 7;
    soff[i] = row * K + ((pos + row) & 7) * 8;
  }
  // Fragment read offsets (tile-invariant): row r, k-chunk kc8 at pos (kc8-r)&7.
  int afo[4][2], bfo[4][2];
#pragma unroll
  for (int i = 0; i < 4; ++i) {
#pragma unroll
    for (int ch = 0; ch < 2; ++ch) {
      int ra = wm + i * 16 + l15;
      int rb = wn + i * 16 + l15;
      int kc8 = ch * 4 + quad;
      afo[i][ch] = ra * 64 + ((kc8 - ra) & 7) * 8;
      bfo[i][ch] = rb * 64 + ((kc8 - rb) & 7) * 8;
    }
  }

  const u16* Ab = A + (long)bm * K;
  const u16* Bb = Bm + (long)bn * K;
  const int nkt = K >> 6;

  for (int kt = 0; kt < nkt; ++kt) {
    __syncthreads();
    const int k0 = kt * 64;
#pragma unroll
    for (int i = 0; i < 4; ++i) gll16(Ab + (long)soff[i] + k0, lA + (t + i * 256) * 8);
#pragma unroll
    for (int i = 0; i < 4; ++i) gll16(Bb + (long)soff[i] + k0, lB + (t + i * 256) * 8);
    __syncthreads();
#pragma unroll
    for (int ch = 0; ch < 2; ++ch) {
      bf16x8 af[4], bfr[4];
#pragma unroll
      for (int i = 0; i < 4; ++i) af[i] = *(const bf16x8*)(lA + afo[i][ch]);
#pragma unroll
      for (int i = 0; i < 4; ++i) bfr[i] = *(const bf16x8*)(lB + bfo[i][ch]);
#pragma unroll
      for (int i = 0; i < 4; ++i)
#pragma unroll
        for (int j = 0; j < 4; ++j)
          acc[i][j] = MFMA_BF16(af[i], bfr[j], acc[i][j]);
    }
  }

  if (bn < 2560) {
    // q/k blocks: natural coalesced writes (all n in block < 2560).
#pragma unroll
    for (int i = 0; i < 4; ++i) {
#pragma unroll
      for (int j = 0; j < 4; ++j) {
#pragma unroll
        for (int r = 0; r < 4; ++r) {
          int m = bm + wm + i * 16 + quad * 4 + r;
          int n = bn + wn + j * 16 + l15;
          u16 hv = f2bf(acc[i][j][r]);
          if (n < 1280) qb[(long)m * 1280 + n] = hv;
          else          kb[(long)m * 1280 + (n - 1280)] = hv;
        }
      }
    }
  } else {
    // V blocks: transpose through LDS (stride 136 u16 -> aligned b128 reads,
    // ~2-way max write conflicts), store vtb coalesced.
    __syncthreads();  // all waves done reading lA/lB
#pragma unroll
    for (int i = 0; i < 4; ++i)
#pragma unroll
      for (int j = 0; j < 4; ++j)
#pragma unroll
        for (int r = 0; r < 4; ++r) {
          int m_loc = wm + i * 16 + quad * 4 + r;
          int n_loc = wn + j * 16 + l15;
          smem[n_loc * 136 + m_loc] = f2bf(acc[i][j][r]);
        }
    __syncthreads();
    const int b = bm >> 11, sbase = bm & 2047;
    u16* dst = vtb + ((long)(b * 1280 + (bn - 2560))) * 2048 + sbase;
#pragma unroll
    for (int it = 0; it < 8; ++it) {
      int idx = it * 256 + t;         // [0,2048)
      int n_loc = idx >> 4;           // [0,128)
      int m0 = (idx & 15) * 8;        // [0,128) step 8
      bf16x8 vv = *(const bf16x8*)(smem + n_loc * 136 + m0);
      *(bf16x8*)(dst + (long)n_loc * 2048 + m0) = vv;
    }
  }
}

// ---------------------------------------------------------------------------
// O-proj GEMM: 128x128 tile, BK=64, rotate-by-row swizzled staging,
// fp32 out + bias.  Grid (32,10).
// ---------------------------------------------------------------------------
__global__ __launch_bounds__(256) void gemm128_o(const u16* __restrict__ A, const u16* __restrict__ Bm,
                                                 float* __restrict__ outf,
                                                 const float* __restrict__ bias, int K) {
  __shared__ __align__(16) u16 lA[128 * 64];
  __shared__ __align__(16) u16 lB[128 * 64];
  const int t = threadIdx.x;
  const int lane = t & 63;
  const int l15 = lane & 15, quad = lane >> 4;
  const int wid = t >> 6;
  const int wm = (wid >> 1) * 64;
  const int wn = (wid & 1) * 64;
  const int bm = blockIdx.x * 128;
  const int bn = blockIdx.y * 128;
  floatx4 acc[4][4] = {};

  int soff[4];
#pragma unroll
  for (int i = 0; i < 4; ++i) {
    int c = t + i * 256;
    int row = c >> 3, pos = c & 7;
    soff[i] = row * K + ((pos + row) & 7) * 8;
  }
  int afo[4][2], bfo[4][2];
#pragma unroll
  for (int i = 0; i < 4; ++i) {
#pragma unroll
    for (int ch = 0; ch < 2; ++ch) {
      int ra = wm + i * 16 + l15;
      int rb = wn + i * 16 + l15;
      int kc8 = ch * 4 + quad;
      afo[i][ch] = ra * 64 + ((kc8 - ra) & 7) * 8;
      bfo[i][ch] = rb * 64 + ((kc8 - rb) & 7) * 8;
    }
  }

  const u16* Ab = A + (long)bm * K;
  const u16* Bb = Bm + (long)bn * K;
  const int nkt = K >> 6;

  for (int kt = 0; kt < nkt; ++kt) {
    __syncthreads();
    const int k0 = kt * 64;
#pragma unroll
    for (int i = 0; i < 4; ++i) gll16(Ab + (long)soff[i] + k0, lA + (t + i * 256) * 8);
#pragma unroll
    for (int i = 0; i < 4; ++i) gll16(Bb + (long)soff[i] + k0, lB + (t + i * 256) * 8);
    __syncthreads();
#pragma unroll
    for (int ch = 0; ch < 2; ++ch) {
      bf16x8 af[4], bfr[4];
#pragma unroll
      for (int i = 0; i < 4; ++i) af[i] = *(const bf16x8*)(lA + afo[i][ch]);
#pragma unroll
      for (int i = 0; i < 4; ++i) bfr[i] = *(const bf16x8*)(lB + bfo[i][ch]);
#pragma unroll
      for (int i = 0; i < 4; ++i)
#pragma unroll
        for (int j = 0; j < 4; ++j)
          acc[i][j] = MFMA_BF16(af[i], bfr[j], acc[i][j]);
    }
  }

#pragma unroll
  for (int i = 0; i < 4; ++i) {
#pragma unroll
    for (int j = 0; j < 4; ++j) {
#pragma unroll
      for (int r = 0; r < 4; ++r) {
        int m = bm + wm + i * 16 + quad * 4 + r;
        int n = bn + wn + j * 16 + l15;
        outf[(long)m * 1280 + n] = acc[i][j][r] + bias[n];
      }
    }
  }
}

// ---------------------------------------------------------------------------
// Flash attention v8 (unchanged from R5): T15 cross-tile pipeline + rot3
// K swizzle + XCD block swizzle.  LDS 80 KB.
// ---------------------------------------------------------------------------
__global__ __launch_bounds__(512) void flash_attn(const u16* __restrict__ qb,
                                                  const u16* __restrict__ kb,
                                                  const u16* __restrict__ vtb,
                                                  u16* __restrict__ attn) {
  const int D = 1280, HD = 160;
  __shared__ __align__(16) u16 kv_lds[2][20480];  // K 10240 | V 10240 per buf
  const int t = threadIdx.x, lane = t & 63, wid = t >> 6;
  const int l31 = lane & 31, hi = lane >> 5;
  const int rg = wid >> 1, kh = wid & 1;
  const int lflat = blockIdx.y * 16 + blockIdx.x;
  const int vswz = (lflat & 7) * 32 + (lflat >> 3);
  const int qi = vswz & 15, bh = vswz >> 4;
  const int b = bh >> 3, h = bh & 7;
  const int q0 = qi * 128 + rg * 32;
  const float kS = 0.11404582025f;

  bf16x8 aq[10];
  {
    const u16* qg = qb + ((long)(b * 2048 + q0 + l31)) * D + h * HD + hi * 8;
#pragma unroll
    for (int kw = 0; kw < 10; ++kw) aq[kw] = *(const bf16x8*)(qg + kw * 16);
  }

  const u16* sg[5];
  int sadv[5];
#pragma unroll
  for (int i = 0; i < 5; ++i) {
    int c = t + i * 512;
    if (c < 1280) {
      int key = c / 20, pos = c - key * 20;
      int g = pos - (3 * key) % 20;
      if (g < 0) g += 20;
      sg[i] = kb + ((long)(b * 2048 + key)) * D + h * HD + g * 8;
      sadv[i] = 64 * D;
    } else {
      int c2 = c - 1280;
      int vrow = c2 >> 3, swz = c2 & 7;
      int vcol = swz ^ (vrow & 7);
      sg[i] = vtb + ((long)(b * 1280 + h * HD + vrow)) * 2048 + vcol * 8;
      sadv[i] = 64;
    }
  }

  int kfo[10];
  {
    int key = kh * 32 + l31;
    int r3 = (3 * key) % 20;
#pragma unroll
    for (int kw = 0; kw < 10; ++kw) {
      int g = kw * 2 + hi;
      int pos = g + r3;
      if (pos >= 20) pos -= 20;
      kfo[kw] = (key * 20 + pos) * 8;
    }
  }
  int vfo[5][2];
#pragma unroll
  for (int db = 0; db < 5; ++db) {
#pragma unroll
    for (int w = 0; w < 2; ++w) {
      int d = db * 32 + l31;
      int gc = kh * 4 + w * 2 + hi;
      int sw = gc ^ (d & 7);
      vfo[db][w] = 10240 + (d * 8 + sw) * 8;
    }
  }

  float l_sum = 0.f;
  floatx16 o_acc[5] = {};
  bf16x8 paA = {}, paB = {};

  gll16(sg[0], &kv_lds[0][t * 8]);           sg[0] += sadv[0];
  gll16(sg[1], &kv_lds[0][(t + 512) * 8]);   sg[1] += sadv[1];
  if (wid < 4) { gll16(sg[2], &kv_lds[0][(t + 1024) * 8]); sg[2] += sadv[2]; }

  for (int kt0 = 0; kt0 < 32; ++kt0) {
    u16* kd = &kv_lds[(kt0 + 1) & 1][0];
    u16* vd = &kv_lds[kt0 & 1][0];
    if (kt0 < 31) {
      gll16(sg[0], kd + t * 8);          sg[0] += sadv[0];
      gll16(sg[1], kd + (t + 512) * 8);  sg[1] += sadv[1];
      if (wid < 4) { gll16(sg[2], kd + (t + 1024) * 8); sg[2] += sadv[2]; }
    }
    if (wid >= 4) { gll16(sg[2], vd + (t + 1024) * 8); sg[2] += sadv[2]; }
    gll16(sg[3], vd + (t + 1536) * 8);  sg[3] += sadv[3];
    gll16(sg[4], vd + (t + 2048) * 8);  sg[4] += sadv[4];

    if (kt0 < 31) asm volatile("s_waitcnt vmcnt(5)" ::: "memory");
    else          asm volatile("s_waitcnt vmcnt(0)" ::: "memory");
    __builtin_amdgcn_s_barrier();
    __builtin_amdgcn_sched_barrier(0);

    const u16* kbase = &kv_lds[kt0 & 1][0];
    const u16* vbase = &kv_lds[(kt0 + 1) & 1][0];  // holds V(t-1)

    floatx16 s0 = {}, s1 = {};
#pragma unroll
    for (int kw = 0; kw < 5; ++kw) {
      bf16x8 k0 = *(const bf16x8*)(kbase + kfo[kw * 2]);
      bf16x8 k1 = *(const bf16x8*)(kbase + kfo[kw * 2 + 1]);
      s0 = MFMA32(k0, aq[kw * 2], s0);
      s1 = MFMA32(k1, aq[kw * 2 + 1], s1);
    }

    if (kt0 > 0) {
#pragma unroll
      for (int db = 0; db < 5; ++db) {
        bf16x8 v0 = *(const bf16x8*)(vbase + vfo[db][0]);
        bf16x8 v1 = *(const bf16x8*)(vbase + vfo[db][1]);
        o_acc[db] = MFMA32(paA, v0, o_acc[db]);
        o_acc[db] = MFMA32(paB, v1, o_acc[db]);
      }
    }

    float p[16];
#pragma unroll
    for (int r = 0; r < 16; ++r) {
      p[r] = __builtin_exp2f(fminf((s0[r] + s1[r]) * kS, 80.f));
      l_sum += p[r];
    }
    u32 c01 = cvtpk(p[0], p[1]),  c23 = cvtpk(p[2], p[3]);
    u32 c45 = cvtpk(p[4], p[5]),  c67 = cvtpk(p[6], p[7]);
    u32 c89 = cvtpk(p[8], p[9]),  cAB = cvtpk(p[10], p[11]);
    u32 cCD = cvtpk(p[12], p[13]), cEF = cvtpk(p[14], p[15]);
    u32x2 r02 = __builtin_amdgcn_permlane32_swap(c01, c45, false, false);
    u32x2 r13 = __builtin_amdgcn_permlane32_swap(c23, c67, false, false);
    u32x2 r46 = __builtin_amdgcn_permlane32_swap(c89, cCD, false, false);
    u32x2 r57 = __builtin_amdgcn_permlane32_swap(cAB, cEF, false, false);
    u32x4 pk0 = {r02[0], r13[0], r02[1], r13[1]};
    u32x4 pk1 = {r46[0], r57[0], r46[1], r57[1]};
    paA = __builtin_bit_cast(bf16x8, pk0);
    paB = __builtin_bit_cast(bf16x8, pk1);

    __builtin_amdgcn_sched_barrier(0);
    __builtin_amdgcn_s_barrier();
  }

  {
    const u16* vbase = &kv_lds[1][0];
#pragma unroll
    for (int db = 0; db < 5; ++db) {
      bf16x8 v0 = *(const bf16x8*)(vbase + vfo[db][0]);
      bf16x8 v1 = *(const bf16x8*)(vbase + vfo[db][1]);
      o_acc[db] = MFMA32(paA, v0, o_acc[db]);
      o_acc[db] = MFMA32(paB, v1, o_acc[db]);
    }
  }
  __syncthreads();

  float* lscr = (float*)&kv_lds[0][0];
  lscr[wid * 64 + lane] = l_sum;
  __syncthreads();
  float rl[16];
#pragma unroll
  for (int r = 0; r < 16; ++r) {
    int q32 = (r & 3) + 8 * (r >> 2) + 4 * hi;
    float tot = lscr[(rg * 2 + 0) * 64 + q32] + lscr[(rg * 2 + 0) * 64 + q32 + 32]
              + lscr[(rg * 2 + 1) * 64 + q32] + lscr[(rg * 2 + 1) * 64 + q32 + 32];
    rl[r] = 1.0f / tot;
  }
  __syncthreads();
  float* oscr = (float*)&kv_lds[0][0];
  if (kh == 1) {
#pragma unroll
    for (int db = 0; db < 5; ++db)
#pragma unroll
      for (int r = 0; r < 16; ++r)
        oscr[rg * 5120 + (db * 16 + r) * 64 + lane] = o_acc[db][r];
  }
  __syncthreads();
  if (kh == 0) {
#pragma unroll
    for (int db = 0; db < 5; ++db) {
#pragma unroll
      for (int r = 0; r < 16; ++r) {
        float v = (o_acc[db][r] + oscr[rg * 5120 + (db * 16 + r) * 64 + lane]) * rl[r];
        int row = q0 + (r & 3) + 8 * (r >> 2) + 4 * hi;
        int col = h * HD + db * 32 + l31;
        attn[((long)(b * 2048 + row)) * D + col] = f2bf(v);
      }
    }
  }
}

// ---------------------------------------------------------------------------
// Launcher (5 kernels).  Workspace (~76.2 MB):
//   xb @0 | weff_qkv @10485760 | weff_o @20316160 | qbuf @23592960
//   kbuf @34078720 | vtb @44564480 | attn @55050240 | down_f @65536000
//   up_f @65617920
// ---------------------------------------------------------------------------
extern "C" void kernel_launch(void* const* d_in, const int* in_sizes, int n_in,
                              void* d_out, int out_size, void* d_ws, size_t ws_size,
                              hipStream_t stream) {
  const float* x   = (const float*)d_in[0];
  const float* pal = (const float*)d_in[1];
  const float* Wq  = (const float*)d_in[2];
  const float* Wk  = (const float*)d_in[3];
  const float* Wv  = (const float*)d_in[4];
  const float* Wo  = (const float*)d_in[5];
  const float* bo  = (const float*)d_in[6];
  const float* qd  = (const float*)d_in[7];
  const float* qu  = (const float*)d_in[8];
  const float* kd  = (const float*)d_in[9];
  const float* ku  = (const float*)d_in[10];
  const float* vd  = (const float*)d_in[11];
  const float* vu  = (const float*)d_in[12];
  const float* od  = (const float*)d_in[13];
  const float* ou  = (const float*)d_in[14];
  float* out = (float*)d_out;

  char* ws = (char*)d_ws;
  u16* xb       = (u16*)(ws);
  u16* weff_qkv = (u16*)(ws + 10485760);
  u16* weff_o   = (u16*)(ws + 20316160);
  u16* qbuf     = (u16*)(ws + 23592960);
  u16* kbuf     = (u16*)(ws + 34078720);
  u16* vtb      = (u16*)(ws + 44564480);
  u16* attn     = (u16*)(ws + 55050240);
  float* down_f = (float*)(ws + 65536000);
  float* up_f   = (float*)(ws + 65617920);

  prep_downup<<<160, 256, 0, stream>>>(pal, qd, qu, kd, ku, vd, vu, od, ou, down_f, up_f);
  build_weff_cvtx<<<30720, 256, 0, stream>>>(Wq, Wk, Wv, Wo, down_f, up_f, weff_qkv, weff_o,
                                             (const float4*)x, (ushort4*)xb);
  gemm128_qkv<<<dim3(32, 30), 256, 0, stream>>>(xb, weff_qkv, qbuf, kbuf, vtb, 1280);
  flash_attn<<<dim3(16, 16), 512, 0, stream>>>(qbuf, kbuf, vtb, attn);
  gemm128_o<<<dim3(32, 10), 256, 0, stream>>>(attn, weff_o, out, bo, 1280);
}